// Round 1
// baseline (362.649 us; speedup 1.0000x reference)
//
#include <hip/hip_runtime.h>
#include <hip/hip_bf16.h>

#define D 128
#define WSTRIDE 132   // padded LDS stride for W (2-way bank conflict max)

// ---------------- CSR build ----------------

__global__ void hist_kernel(const int* __restrict__ dst, int* __restrict__ deg, int E) {
    int i = blockIdx.x * blockDim.x + threadIdx.x;
    int stride = gridDim.x * blockDim.x;
    for (; i < E; i += stride)
        atomicAdd(&deg[dst[i]], 1);
}

// single-block exclusive scan of deg[0..n) -> row_ptr[0..n], also copies to cursor
__global__ void scan_kernel(const int* __restrict__ deg, int* __restrict__ row_ptr,
                            int* __restrict__ cursor, int n) {
    __shared__ int sums[1024];
    int t = threadIdx.x;
    int chunk = (n + 1023) >> 10;
    int beg = t * chunk;
    int end = beg + chunk; if (end > n) end = n;
    int s = 0;
    for (int i = beg; i < end; ++i) s += deg[i];
    sums[t] = s;
    __syncthreads();
    for (int off = 1; off < 1024; off <<= 1) {
        int v = (t >= off) ? sums[t - off] : 0;
        __syncthreads();
        sums[t] += v;
        __syncthreads();
    }
    int run = (t == 0) ? 0 : sums[t - 1];
    for (int i = beg; i < end; ++i) {
        row_ptr[i] = run;
        cursor[i] = run;
        run += deg[i];
    }
    if (t == 1023) row_ptr[n] = sums[1023];
}

__global__ void fill_kernel(const int* __restrict__ src, const int* __restrict__ dst,
                            int* __restrict__ cursor, int* __restrict__ csr_src, int E) {
    int i = blockIdx.x * blockDim.x + threadIdx.x;
    int stride = gridDim.x * blockDim.x;
    for (; i < E; i += stride) {
        int p = atomicAdd(&cursor[dst[i]], 1);
        csr_src[p] = src[i];
    }
}

// ---------------- aggregation: h[v] = feature[v] + sum_{u in csr[v]} feature[u] ----------------
// one wave (64 lanes) per node; lane covers 2 floats -> one 512B row per load instruction

__global__ void agg_kernel(const float* __restrict__ feature,
                           const int* __restrict__ row_ptr,
                           const int* __restrict__ csr_src,
                           float* __restrict__ h, int n) {
    int gtid   = blockIdx.x * blockDim.x + threadIdx.x;
    int wave   = gtid >> 6;
    int lane   = threadIdx.x & 63;
    int nwaves = (gridDim.x * blockDim.x) >> 6;
    int off    = lane * 2;

    for (int v = wave; v < n; v += nwaves) {
        int beg = row_ptr[v];
        int end = row_ptr[v + 1];
        float2 acc = *(const float2*)&feature[(size_t)v * D + off];
        int e = beg;
        for (; e + 1 < end; e += 2) {  // 2-wide to break the load->add dep chain
            int u0 = csr_src[e];
            int u1 = csr_src[e + 1];
            float2 f0 = *(const float2*)&feature[(size_t)u0 * D + off];
            float2 f1 = *(const float2*)&feature[(size_t)u1 * D + off];
            acc.x += f0.x + f1.x;
            acc.y += f0.y + f1.y;
        }
        if (e < end) {
            int u = csr_src[e];
            float2 f = *(const float2*)&feature[(size_t)u * D + off];
            acc.x += f.x;
            acc.y += f.y;
        }
        *(float2*)&h[(size_t)v * D + off] = acc;
    }
}

// ---------------- GEMM: out = h @ W^T + b ----------------
// block = 256 threads, 64 nodes per block. W staged in LDS (stride 132).
// thread (tx = t&15, tyg = t>>4): rows v0+tyg*4 .. +4, cols tx + 16*jj (jj<8)

__global__ __launch_bounds__(256, 2) void gemm_kernel(
        const float* __restrict__ h, const float* __restrict__ W,
        const float* __restrict__ b, float* __restrict__ out, int n) {
    __shared__ float ws[D * WSTRIDE];
    int t = threadIdx.x;

    // stage W: 4096 float4s, coalesced
    #pragma unroll
    for (int i = 0; i < 16; ++i) {
        int f = t + 256 * i;          // float4 index
        int j = f >> 5;               // row
        int k = (f & 31) * 4;         // col
        float4 val = *(const float4*)&W[j * D + k];
        *(float4*)&ws[j * WSTRIDE + k] = val;
    }
    __syncthreads();

    int tx  = t & 15;
    int tyg = t >> 4;
    int v0  = blockIdx.x * 64 + tyg * 4;
    bool full = (blockIdx.x * 64 + 64) <= n;

    float acc[4][8];
    #pragma unroll
    for (int vv = 0; vv < 4; ++vv)
        #pragma unroll
        for (int jj = 0; jj < 8; ++jj) acc[vv][jj] = 0.0f;

    for (int k0 = 0; k0 < D; k0 += 4) {
        float4 hv[4];
        #pragma unroll
        for (int vv = 0; vv < 4; ++vv) {
            int v = v0 + vv;
            if (full || v < n)
                hv[vv] = *(const float4*)&h[(size_t)v * D + k0];
            else
                hv[vv] = make_float4(0.f, 0.f, 0.f, 0.f);
        }
        float4 wv[8];
        #pragma unroll
        for (int jj = 0; jj < 8; ++jj)
            wv[jj] = *(const float4*)&ws[(tx + 16 * jj) * WSTRIDE + k0];
        #pragma unroll
        for (int vv = 0; vv < 4; ++vv)
            #pragma unroll
            for (int jj = 0; jj < 8; ++jj) {
                acc[vv][jj] += hv[vv].x * wv[jj].x;
                acc[vv][jj] += hv[vv].y * wv[jj].y;
                acc[vv][jj] += hv[vv].z * wv[jj].z;
                acc[vv][jj] += hv[vv].w * wv[jj].w;
            }
    }

    #pragma unroll
    for (int vv = 0; vv < 4; ++vv) {
        int v = v0 + vv;
        if (v >= n) break;
        #pragma unroll
        for (int jj = 0; jj < 8; ++jj) {
            int j = tx + 16 * jj;
            out[(size_t)v * D + j] = acc[vv][jj] + b[j];
        }
    }
}

// ---------------- launch ----------------

extern "C" void kernel_launch(void* const* d_in, const int* in_sizes, int n_in,
                              void* d_out, int out_size, void* d_ws, size_t ws_size,
                              hipStream_t stream) {
    const float* feature = (const float*)d_in[0];
    const int*   src     = (const int*)d_in[1];
    const int*   dst     = (const int*)d_in[2];
    const float* W       = (const float*)d_in[3];
    const float* b       = (const float*)d_in[4];
    float*       out     = (float*)d_out;

    const int N = in_sizes[0] / D;
    const int E = in_sizes[1];

    // workspace layout
    char* w = (char*)d_ws;
    float* h       = (float*)w;                     w += (size_t)N * D * sizeof(float);
    int*   row_ptr = (int*)w;                       w += (size_t)(N + 1) * sizeof(int);
    int*   cursor  = (int*)w;                       w += (size_t)N * sizeof(int);
    int*   deg     = (int*)w;                       w += (size_t)N * sizeof(int);
    int*   csr_src = (int*)w;

    hipMemsetAsync(deg, 0, (size_t)N * sizeof(int), stream);

    int eblocks = (E + 255) / 256;
    hist_kernel<<<eblocks, 256, 0, stream>>>(dst, deg, E);
    scan_kernel<<<1, 1024, 0, stream>>>(deg, row_ptr, cursor, N);
    fill_kernel<<<eblocks, 256, 0, stream>>>(src, dst, cursor, csr_src, E);

    agg_kernel<<<2048, 256, 0, stream>>>(feature, row_ptr, csr_src, h, N);

    int gblocks = (N + 63) / 64;
    gemm_kernel<<<gblocks, 256, 0, stream>>>(h, W, b, out, N);
}

// Round 3
// 263.995 us; speedup vs baseline: 1.3737x; 1.3737x over previous
//
#include <hip/hip_runtime.h>
#include <hip/hip_bf16.h>

#define D 128
#define WSTRIDE 132   // padded LDS stride for W (2-way bank conflict max)

#define SCAN_NB 64
#define SCAN_BT 256

// ---------------- CSR build ----------------

__global__ void hist_kernel(const int* __restrict__ dst, int* __restrict__ deg, int E) {
    int i = blockIdx.x * blockDim.x + threadIdx.x;
    int stride = gridDim.x * blockDim.x;
    for (; i < E; i += stride)
        atomicAdd(&deg[dst[i]], 1);
}

// pass 1: per-block sum of deg over contiguous per-thread chunks
__global__ void scan_part_kernel(const int* __restrict__ deg, int* __restrict__ blocksum, int n) {
    __shared__ int s[SCAN_BT];
    int t    = threadIdx.x;
    int tot  = gridDim.x * blockDim.x;
    int chunk = (n + tot - 1) / tot;
    int gt   = blockIdx.x * blockDim.x + t;
    int beg  = gt * chunk;
    int end  = beg + chunk; if (end > n) end = n;
    int sum = 0;
    for (int i = beg; i < end; ++i) sum += deg[i];
    s[t] = sum;
    __syncthreads();
    for (int off = SCAN_BT >> 1; off > 0; off >>= 1) {
        if (t < off) s[t] += s[t + off];
        __syncthreads();
    }
    if (t == 0) blocksum[blockIdx.x] = s[0];
}

// pass 2: exclusive scan of SCAN_NB block sums (single wave)
__global__ void scan_blocksum_kernel(int* __restrict__ blocksum) {
    __shared__ int s[SCAN_NB];
    int t = threadIdx.x;
    int v = blocksum[t];
    s[t] = v;
    __syncthreads();
    for (int off = 1; off < SCAN_NB; off <<= 1) {
        int u = (t >= off) ? s[t - off] : 0;
        __syncthreads();
        s[t] += u;
        __syncthreads();
    }
    blocksum[t] = s[t] - v;   // exclusive
}

// pass 3: per-block LDS scan of thread sums + block offset -> write row_ptr & cursor
__global__ void scan_write_kernel(const int* __restrict__ deg,
                                  const int* __restrict__ blocksum,
                                  int* __restrict__ row_ptr,
                                  int* __restrict__ cursor, int n, int E) {
    __shared__ int s[SCAN_BT];
    int t    = threadIdx.x;
    int tot  = gridDim.x * blockDim.x;
    int chunk = (n + tot - 1) / tot;
    int gt   = blockIdx.x * blockDim.x + t;
    int beg  = gt * chunk;
    int end  = beg + chunk; if (end > n) end = n;
    int sum = 0;
    for (int i = beg; i < end; ++i) sum += deg[i];
    s[t] = sum;
    __syncthreads();
    for (int off = 1; off < SCAN_BT; off <<= 1) {
        int u = (t >= off) ? s[t - off] : 0;
        __syncthreads();
        s[t] += u;
        __syncthreads();
    }
    int run = blocksum[blockIdx.x] + s[t] - sum;   // exclusive prefix for this thread
    for (int i = beg; i < end; ++i) {
        row_ptr[i] = run;
        cursor[i]  = run;
        run += deg[i];
    }
    if (gt == 0) row_ptr[n] = E;   // total degree == E by construction
}

__global__ void fill_kernel(const int* __restrict__ src, const int* __restrict__ dst,
                            int* __restrict__ cursor, int* __restrict__ csr_src, int E) {
    int i = blockIdx.x * blockDim.x + threadIdx.x;
    int stride = gridDim.x * blockDim.x;
    for (; i < E; i += stride) {
        int p = atomicAdd(&cursor[dst[i]], 1);
        csr_src[p] = src[i];
    }
}

// ---------------- aggregation: h[v] = feature[v] + sum_{u in csr[v]} feature[u] ----------------
// one wave (64 lanes) per node; lane covers 2 floats -> one 512B row per load instruction

__global__ void agg_kernel(const float* __restrict__ feature,
                           const int* __restrict__ row_ptr,
                           const int* __restrict__ csr_src,
                           float* __restrict__ h, int n) {
    int gtid   = blockIdx.x * blockDim.x + threadIdx.x;
    int wave   = gtid >> 6;
    int lane   = threadIdx.x & 63;
    int nwaves = (gridDim.x * blockDim.x) >> 6;
    int off    = lane * 2;

    for (int v = wave; v < n; v += nwaves) {
        int beg = row_ptr[v];
        int end = row_ptr[v + 1];
        float2 acc = *(const float2*)&feature[(size_t)v * D + off];
        int e = beg;
        for (; e + 1 < end; e += 2) {  // 2-wide to break the load->add dep chain
            int u0 = csr_src[e];
            int u1 = csr_src[e + 1];
            float2 f0 = *(const float2*)&feature[(size_t)u0 * D + off];
            float2 f1 = *(const float2*)&feature[(size_t)u1 * D + off];
            acc.x += f0.x + f1.x;
            acc.y += f0.y + f1.y;
        }
        if (e < end) {
            int u = csr_src[e];
            float2 f = *(const float2*)&feature[(size_t)u * D + off];
            acc.x += f.x;
            acc.y += f.y;
        }
        *(float2*)&h[(size_t)v * D + off] = acc;
    }
}

// ---------------- GEMM: out = h @ W^T + b ----------------
// block = 256 threads, 64 nodes per block. W staged in LDS (stride 132).
// thread (tx = t&15, tyg = t>>4): rows v0+tyg*4 .. +4, cols tx + 16*jj (jj<8)

__global__ __launch_bounds__(256, 2) void gemm_kernel(
        const float* __restrict__ h, const float* __restrict__ W,
        const float* __restrict__ b, float* __restrict__ out, int n) {
    __shared__ float ws[D * WSTRIDE];
    int t = threadIdx.x;

    // stage W: 4096 float4s, coalesced
    #pragma unroll
    for (int i = 0; i < 16; ++i) {
        int f = t + 256 * i;          // float4 index
        int j = f >> 5;               // row
        int k = (f & 31) * 4;         // col
        float4 val = *(const float4*)&W[j * D + k];
        *(float4*)&ws[j * WSTRIDE + k] = val;
    }
    __syncthreads();

    int tx  = t & 15;
    int tyg = t >> 4;
    int v0  = blockIdx.x * 64 + tyg * 4;
    bool full = (blockIdx.x * 64 + 64) <= n;

    float acc[4][8];
    #pragma unroll
    for (int vv = 0; vv < 4; ++vv)
        #pragma unroll
        for (int jj = 0; jj < 8; ++jj) acc[vv][jj] = 0.0f;

    for (int k0 = 0; k0 < D; k0 += 4) {
        float4 hv[4];
        #pragma unroll
        for (int vv = 0; vv < 4; ++vv) {
            int v = v0 + vv;
            if (full || v < n)
                hv[vv] = *(const float4*)&h[(size_t)v * D + k0];
            else
                hv[vv] = make_float4(0.f, 0.f, 0.f, 0.f);
        }
        float4 wv[8];
        #pragma unroll
        for (int jj = 0; jj < 8; ++jj)
            wv[jj] = *(const float4*)&ws[(tx + 16 * jj) * WSTRIDE + k0];
        #pragma unroll
        for (int vv = 0; vv < 4; ++vv)
            #pragma unroll
            for (int jj = 0; jj < 8; ++jj) {
                acc[vv][jj] += hv[vv].x * wv[jj].x;
                acc[vv][jj] += hv[vv].y * wv[jj].y;
                acc[vv][jj] += hv[vv].z * wv[jj].z;
                acc[vv][jj] += hv[vv].w * wv[jj].w;
            }
    }

    #pragma unroll
    for (int vv = 0; vv < 4; ++vv) {
        int v = v0 + vv;
        if (v >= n) break;
        #pragma unroll
        for (int jj = 0; jj < 8; ++jj) {
            int j = tx + 16 * jj;
            out[(size_t)v * D + j] = acc[vv][jj] + b[j];
        }
    }
}

// ---------------- launch ----------------

extern "C" void kernel_launch(void* const* d_in, const int* in_sizes, int n_in,
                              void* d_out, int out_size, void* d_ws, size_t ws_size,
                              hipStream_t stream) {
    const float* feature = (const float*)d_in[0];
    const int*   src     = (const int*)d_in[1];
    const int*   dst     = (const int*)d_in[2];
    const float* W       = (const float*)d_in[3];
    const float* b       = (const float*)d_in[4];
    float*       out     = (float*)d_out;

    const int N = in_sizes[0] / D;
    const int E = in_sizes[1];

    // workspace layout
    char* w = (char*)d_ws;
    float* h        = (float*)w;                    w += (size_t)N * D * sizeof(float);
    int*   row_ptr  = (int*)w;                      w += (size_t)(N + 1) * sizeof(int);
    int*   cursor   = (int*)w;                      w += (size_t)N * sizeof(int);
    int*   deg      = (int*)w;                      w += (size_t)N * sizeof(int);
    int*   blocksum = (int*)w;                      w += (size_t)SCAN_NB * sizeof(int);
    int*   csr_src  = (int*)w;

    hipMemsetAsync(deg, 0, (size_t)N * sizeof(int), stream);

    int eblocks = (E + 255) / 256;
    hist_kernel<<<eblocks, 256, 0, stream>>>(dst, deg, E);
    scan_part_kernel<<<SCAN_NB, SCAN_BT, 0, stream>>>(deg, blocksum, N);
    scan_blocksum_kernel<<<1, SCAN_NB, 0, stream>>>(blocksum);
    scan_write_kernel<<<SCAN_NB, SCAN_BT, 0, stream>>>(deg, blocksum, row_ptr, cursor, N, E);
    fill_kernel<<<eblocks, 256, 0, stream>>>(src, dst, cursor, csr_src, E);

    agg_kernel<<<2048, 256, 0, stream>>>(feature, row_ptr, csr_src, h, N);

    int gblocks = (N + 63) / 64;
    gemm_kernel<<<gblocks, 256, 0, stream>>>(h, W, b, out, N);
}

// Round 4
// 254.120 us; speedup vs baseline: 1.4271x; 1.0389x over previous
//
#include <hip/hip_runtime.h>
#include <hip/hip_bf16.h>

#define D 128
#define WSTRIDE 132   // padded LDS stride for W (2-way bank conflict max)

#define SCAN_NB 64
#define SCAN_BT 256

// ---------------- CSR build ----------------

__global__ void hist_kernel(const int* __restrict__ dst, int* __restrict__ deg, int E) {
    int i = blockIdx.x * blockDim.x + threadIdx.x;
    int stride = gridDim.x * blockDim.x;
    for (; i < E; i += stride)
        atomicAdd(&deg[dst[i]], 1);
}

// pass 1: per-block sum of deg over contiguous per-thread chunks
__global__ void scan_part_kernel(const int* __restrict__ deg, int* __restrict__ blocksum, int n) {
    __shared__ int s[SCAN_BT];
    int t    = threadIdx.x;
    int tot  = gridDim.x * blockDim.x;
    int chunk = (n + tot - 1) / tot;
    int gt   = blockIdx.x * blockDim.x + t;
    int beg  = gt * chunk;
    int end  = beg + chunk; if (end > n) end = n;
    int sum = 0;
    for (int i = beg; i < end; ++i) sum += deg[i];
    s[t] = sum;
    __syncthreads();
    for (int off = SCAN_BT >> 1; off > 0; off >>= 1) {
        if (t < off) s[t] += s[t + off];
        __syncthreads();
    }
    if (t == 0) blocksum[blockIdx.x] = s[0];
}

// pass 2: exclusive scan of SCAN_NB block sums (single wave)
__global__ void scan_blocksum_kernel(int* __restrict__ blocksum) {
    __shared__ int s[SCAN_NB];
    int t = threadIdx.x;
    int v = blocksum[t];
    s[t] = v;
    __syncthreads();
    for (int off = 1; off < SCAN_NB; off <<= 1) {
        int u = (t >= off) ? s[t - off] : 0;
        __syncthreads();
        s[t] += u;
        __syncthreads();
    }
    blocksum[t] = s[t] - v;   // exclusive
}

// pass 3: per-block LDS scan of thread sums + block offset -> write row_ptr & cursor
__global__ void scan_write_kernel(const int* __restrict__ deg,
                                  const int* __restrict__ blocksum,
                                  int* __restrict__ row_ptr,
                                  int* __restrict__ cursor, int n, int E) {
    __shared__ int s[SCAN_BT];
    int t    = threadIdx.x;
    int tot  = gridDim.x * blockDim.x;
    int chunk = (n + tot - 1) / tot;
    int gt   = blockIdx.x * blockDim.x + t;
    int beg  = gt * chunk;
    int end  = beg + chunk; if (end > n) end = n;
    int sum = 0;
    for (int i = beg; i < end; ++i) sum += deg[i];
    s[t] = sum;
    __syncthreads();
    for (int off = 1; off < SCAN_BT; off <<= 1) {
        int u = (t >= off) ? s[t - off] : 0;
        __syncthreads();
        s[t] += u;
        __syncthreads();
    }
    int run = blocksum[blockIdx.x] + s[t] - sum;   // exclusive prefix for this thread
    for (int i = beg; i < end; ++i) {
        row_ptr[i] = run;
        cursor[i]  = run;
        run += deg[i];
    }
    if (gt == 0) row_ptr[n] = E;   // total degree == E by construction
}

__global__ void fill_kernel(const int* __restrict__ src, const int* __restrict__ dst,
                            int* __restrict__ cursor, int* __restrict__ csr_src, int E) {
    int i = blockIdx.x * blockDim.x + threadIdx.x;
    int stride = gridDim.x * blockDim.x;
    for (; i < E; i += stride) {
        int p = atomicAdd(&cursor[dst[i]], 1);
        csr_src[p] = src[i];
    }
}

// ---------------- aggregation: h[v] = feature[v] + sum_{u in csr[v]} feature[u] ----------------
// one wave (64 lanes) per node; lane covers 2 floats -> one 512B row per load instruction

__global__ void agg_kernel(const float* __restrict__ feature,
                           const int* __restrict__ row_ptr,
                           const int* __restrict__ csr_src,
                           float* __restrict__ h, int n) {
    int gtid   = blockIdx.x * blockDim.x + threadIdx.x;
    int wave   = gtid >> 6;
    int lane   = threadIdx.x & 63;
    int nwaves = (gridDim.x * blockDim.x) >> 6;
    int off    = lane * 2;

    for (int v = wave; v < n; v += nwaves) {
        int beg = row_ptr[v];
        int end = row_ptr[v + 1];
        float2 acc = *(const float2*)&feature[(size_t)v * D + off];
        int e = beg;
        for (; e + 1 < end; e += 2) {  // 2-wide to break the load->add dep chain
            int u0 = csr_src[e];
            int u1 = csr_src[e + 1];
            float2 f0 = *(const float2*)&feature[(size_t)u0 * D + off];
            float2 f1 = *(const float2*)&feature[(size_t)u1 * D + off];
            acc.x += f0.x + f1.x;
            acc.y += f0.y + f1.y;
        }
        if (e < end) {
            int u = csr_src[e];
            float2 f = *(const float2*)&feature[(size_t)u * D + off];
            acc.x += f.x;
            acc.y += f.y;
        }
        *(float2*)&h[(size_t)v * D + off] = acc;
    }
}

// ---------------- GEMM: out = h @ W^T + b ----------------
// block = 256 threads, tile = 64 rows x 64 cols. Half of W (64 cols) in LDS,
// stride 132 -> 33 KiB -> 4 blocks/CU (vs 2 before). Thread (tx=t&15, tyg=t>>4):
// rows v0 = brow+tyg*4 .. +4, cols bcol + tx + 16*jj (jj<4). Branch-free clamped
// h pointers so the k-loop software-pipelines.

__global__ __launch_bounds__(256, 4) void gemm_kernel(
        const float* __restrict__ h, const float* __restrict__ W,
        const float* __restrict__ b, float* __restrict__ out, int n) {
    __shared__ float ws[64 * WSTRIDE];
    int t    = threadIdx.x;
    int bcol = (blockIdx.x & 1) << 6;
    int brow = (blockIdx.x >> 1) << 6;

    // stage 64 rows of W (cols bcol..bcol+63): 2048 float4s, coalesced
    #pragma unroll
    for (int i = 0; i < 8; ++i) {
        int f = t + (i << 8);         // float4 index 0..2047
        int j = f >> 5;               // local col 0..63
        int k = (f & 31) << 2;        // k offset
        *(float4*)&ws[j * WSTRIDE + k] = *(const float4*)&W[(size_t)(bcol + j) * D + k];
    }
    __syncthreads();

    int tx  = t & 15;
    int tyg = t >> 4;
    int v0  = brow + tyg * 4;

    float acc[4][4];
    #pragma unroll
    for (int vv = 0; vv < 4; ++vv)
        #pragma unroll
        for (int jj = 0; jj < 4; ++jj) acc[vv][jj] = 0.0f;

    // branch-free clamped row pointers (rows >= n compute garbage, never stored)
    const float* hp[4];
    #pragma unroll
    for (int vv = 0; vv < 4; ++vv) {
        int v = v0 + vv;
        if (v >= n) v = n - 1;
        hp[vv] = &h[(size_t)v * D];
    }

    #pragma unroll 4
    for (int k0 = 0; k0 < D; k0 += 4) {
        float4 hv[4];
        #pragma unroll
        for (int vv = 0; vv < 4; ++vv)
            hv[vv] = *(const float4*)(hp[vv] + k0);
        float4 wv[4];
        #pragma unroll
        for (int jj = 0; jj < 4; ++jj)
            wv[jj] = *(const float4*)&ws[(tx + (jj << 4)) * WSTRIDE + k0];
        #pragma unroll
        for (int vv = 0; vv < 4; ++vv)
            #pragma unroll
            for (int jj = 0; jj < 4; ++jj) {
                acc[vv][jj] += hv[vv].x * wv[jj].x;
                acc[vv][jj] += hv[vv].y * wv[jj].y;
                acc[vv][jj] += hv[vv].z * wv[jj].z;
                acc[vv][jj] += hv[vv].w * wv[jj].w;
            }
    }

    #pragma unroll
    for (int vv = 0; vv < 4; ++vv) {
        int v = v0 + vv;
        if (v >= n) break;
        #pragma unroll
        for (int jj = 0; jj < 4; ++jj) {
            int j = bcol + tx + (jj << 4);
            out[(size_t)v * D + j] = acc[vv][jj] + b[j];
        }
    }
}

// ---------------- launch ----------------

extern "C" void kernel_launch(void* const* d_in, const int* in_sizes, int n_in,
                              void* d_out, int out_size, void* d_ws, size_t ws_size,
                              hipStream_t stream) {
    const float* feature = (const float*)d_in[0];
    const int*   src     = (const int*)d_in[1];
    const int*   dst     = (const int*)d_in[2];
    const float* W       = (const float*)d_in[3];
    const float* b       = (const float*)d_in[4];
    float*       out     = (float*)d_out;

    const int N = in_sizes[0] / D;
    const int E = in_sizes[1];

    // workspace layout
    char* w = (char*)d_ws;
    float* h        = (float*)w;                    w += (size_t)N * D * sizeof(float);
    int*   row_ptr  = (int*)w;                      w += (size_t)(N + 1) * sizeof(int);
    int*   cursor   = (int*)w;                      w += (size_t)N * sizeof(int);
    int*   deg      = (int*)w;                      w += (size_t)N * sizeof(int);
    int*   blocksum = (int*)w;                      w += (size_t)SCAN_NB * sizeof(int);
    int*   csr_src  = (int*)w;

    hipMemsetAsync(deg, 0, (size_t)N * sizeof(int), stream);

    int eblocks = (E + 255) / 256;
    hist_kernel<<<eblocks, 256, 0, stream>>>(dst, deg, E);
    scan_part_kernel<<<SCAN_NB, SCAN_BT, 0, stream>>>(deg, blocksum, N);
    scan_blocksum_kernel<<<1, SCAN_NB, 0, stream>>>(blocksum);
    scan_write_kernel<<<SCAN_NB, SCAN_BT, 0, stream>>>(deg, blocksum, row_ptr, cursor, N, E);
    fill_kernel<<<eblocks, 256, 0, stream>>>(src, dst, cursor, csr_src, E);

    agg_kernel<<<2048, 256, 0, stream>>>(feature, row_ptr, csr_src, h, N);

    int grblocks = ((N + 63) / 64) * 2;   // row-blocks x 2 column halves
    gemm_kernel<<<grblocks, 256, 0, stream>>>(h, W, b, out, N);
}

// Round 5
// 237.687 us; speedup vs baseline: 1.5257x; 1.0691x over previous
//
#include <hip/hip_runtime.h>
#include <hip/hip_bf16.h>

#define D 128

#define SCAN_NB 64
#define SCAN_BT 256

typedef __bf16 bf16x8 __attribute__((ext_vector_type(8)));
typedef float  f32x4  __attribute__((ext_vector_type(4)));

// ---------------- CSR build ----------------

__global__ void hist_kernel(const int* __restrict__ dst, int* __restrict__ deg, int E) {
    int i = blockIdx.x * blockDim.x + threadIdx.x;
    int stride = gridDim.x * blockDim.x;
    for (; i < E; i += stride)
        atomicAdd(&deg[dst[i]], 1);
}

// pass 1: per-block sum of deg over contiguous per-thread chunks
__global__ void scan_part_kernel(const int* __restrict__ deg, int* __restrict__ blocksum, int n) {
    __shared__ int s[SCAN_BT];
    int t    = threadIdx.x;
    int tot  = gridDim.x * blockDim.x;
    int chunk = (n + tot - 1) / tot;
    int gt   = blockIdx.x * blockDim.x + t;
    int beg  = gt * chunk;
    int end  = beg + chunk; if (end > n) end = n;
    int sum = 0;
    for (int i = beg; i < end; ++i) sum += deg[i];
    s[t] = sum;
    __syncthreads();
    for (int off = SCAN_BT >> 1; off > 0; off >>= 1) {
        if (t < off) s[t] += s[t + off];
        __syncthreads();
    }
    if (t == 0) blocksum[blockIdx.x] = s[0];
}

// pass 2: exclusive scan of SCAN_NB block sums (single wave)
__global__ void scan_blocksum_kernel(int* __restrict__ blocksum) {
    __shared__ int s[SCAN_NB];
    int t = threadIdx.x;
    int v = blocksum[t];
    s[t] = v;
    __syncthreads();
    for (int off = 1; off < SCAN_NB; off <<= 1) {
        int u = (t >= off) ? s[t - off] : 0;
        __syncthreads();
        s[t] += u;
        __syncthreads();
    }
    blocksum[t] = s[t] - v;   // exclusive
}

// pass 3: per-block LDS scan of thread sums + block offset -> write row_ptr & cursor
__global__ void scan_write_kernel(const int* __restrict__ deg,
                                  const int* __restrict__ blocksum,
                                  int* __restrict__ row_ptr,
                                  int* __restrict__ cursor, int n, int E) {
    __shared__ int s[SCAN_BT];
    int t    = threadIdx.x;
    int tot  = gridDim.x * blockDim.x;
    int chunk = (n + tot - 1) / tot;
    int gt   = blockIdx.x * blockDim.x + t;
    int beg  = gt * chunk;
    int end  = beg + chunk; if (end > n) end = n;
    int sum = 0;
    for (int i = beg; i < end; ++i) sum += deg[i];
    s[t] = sum;
    __syncthreads();
    for (int off = 1; off < SCAN_BT; off <<= 1) {
        int u = (t >= off) ? s[t - off] : 0;
        __syncthreads();
        s[t] += u;
        __syncthreads();
    }
    int run = blocksum[blockIdx.x] + s[t] - sum;   // exclusive prefix for this thread
    for (int i = beg; i < end; ++i) {
        row_ptr[i] = run;
        cursor[i]  = run;
        run += deg[i];
    }
    if (gt == 0) row_ptr[n] = E;   // total degree == E by construction
}

__global__ void fill_kernel(const int* __restrict__ src, const int* __restrict__ dst,
                            int* __restrict__ cursor, int* __restrict__ csr_src, int E) {
    int i = blockIdx.x * blockDim.x + threadIdx.x;
    int stride = gridDim.x * blockDim.x;
    for (; i < E; i += stride) {
        int p = atomicAdd(&cursor[dst[i]], 1);
        csr_src[p] = src[i];
    }
}

// ---------------- aggregation: h[v] = feature[v] + sum_{u in csr[v]} feature[u] ----------------
// one wave (64 lanes) per node; lane covers 2 floats -> one 512B row per load instruction

__global__ void agg_kernel(const float* __restrict__ feature,
                           const int* __restrict__ row_ptr,
                           const int* __restrict__ csr_src,
                           float* __restrict__ h, int n) {
    int gtid   = blockIdx.x * blockDim.x + threadIdx.x;
    int wave   = gtid >> 6;
    int lane   = threadIdx.x & 63;
    int nwaves = (gridDim.x * blockDim.x) >> 6;
    int off    = lane * 2;

    for (int v = wave; v < n; v += nwaves) {
        int beg = row_ptr[v];
        int end = row_ptr[v + 1];
        float2 acc = *(const float2*)&feature[(size_t)v * D + off];
        int e = beg;
        for (; e + 1 < end; e += 2) {  // 2-wide to break the load->add dep chain
            int u0 = csr_src[e];
            int u1 = csr_src[e + 1];
            float2 f0 = *(const float2*)&feature[(size_t)u0 * D + off];
            float2 f1 = *(const float2*)&feature[(size_t)u1 * D + off];
            acc.x += f0.x + f1.x;
            acc.y += f0.y + f1.y;
        }
        if (e < end) {
            int u = csr_src[e];
            float2 f = *(const float2*)&feature[(size_t)u * D + off];
            acc.x += f.x;
            acc.y += f.y;
        }
        *(float2*)&h[(size_t)v * D + off] = acc;
    }
}

// ---------------- GEMM via split-bf16 MFMA: out = h @ W^T + b ----------------
// out[v][j] = sum_k h[v][k] * W[j][k]  -> D = A·B with A = h tile (16x32 per
// MFMA), B[k][j] = W[j][k]. Split each f32 operand x = hi + lo (bf16 each);
// compute hi·hi + lo·hi + hi·lo (f32 accum) -> ~2^-18 relative error (≈ f32).
//
// Per wave: 16 rows x all 128 cols. A-frags (h) loaded once: lane reads
// h[m0 + (lane&15)][8*(lane>>4) + 32*ks + 0..7]  (one 32B chunk / kstep).
// B-frags (W) per 16-col tile, same lane pattern on W rows. No LDS.
// C/D layout (verified m89/m91): col = lane&15, row = (lane>>4)*4 + reg.

__global__ void gemm_mfma_kernel(const float* __restrict__ h,
                                 const float* __restrict__ W,
                                 const float* __restrict__ bias,
                                 float* __restrict__ out, int n) {
    int t    = threadIdx.x;
    int lane = t & 63;
    int wv   = t >> 6;                    // wave within block (0..3)
    int m0   = blockIdx.x * 64 + wv * 16; // 16 output rows per wave
    if (m0 >= n) return;

    int idx16 = lane & 15;                // A row / B col / C col within tile
    int kgrp  = lane >> 4;                // k group: k = 8*kgrp + b (+32*ks)

    int arow = m0 + idx16; if (arow >= n) arow = n - 1;   // clamp (never stored)
    const float* hrow = &h[(size_t)arow * D + kgrp * 8];

    // ---- A fragments: hi/lo split, loaded once, reused for all 8 j-tiles ----
    bf16x8 a_hi[4], a_lo[4];
    #pragma unroll
    for (int ks = 0; ks < 4; ++ks) {
        float4 f0 = *(const float4*)(hrow + ks * 32);
        float4 f1 = *(const float4*)(hrow + ks * 32 + 4);
        float f[8] = {f0.x, f0.y, f0.z, f0.w, f1.x, f1.y, f1.z, f1.w};
        #pragma unroll
        for (int i = 0; i < 8; ++i) {
            __bf16 hi = (__bf16)f[i];
            a_hi[ks][i] = hi;
            a_lo[ks][i] = (__bf16)(f[i] - (float)hi);
        }
    }

    // ---- loop over 8 column tiles of 16 ----
    #pragma unroll 2
    for (int jt = 0; jt < 8; ++jt) {
        int j0 = jt * 16;
        const float* wrow = &W[(size_t)(j0 + idx16) * D + kgrp * 8];

        f32x4 acc = {0.f, 0.f, 0.f, 0.f};
        #pragma unroll
        for (int ks = 0; ks < 4; ++ks) {
            float4 f0 = *(const float4*)(wrow + ks * 32);
            float4 f1 = *(const float4*)(wrow + ks * 32 + 4);
            float f[8] = {f0.x, f0.y, f0.z, f0.w, f1.x, f1.y, f1.z, f1.w};
            bf16x8 b_hi, b_lo;
            #pragma unroll
            for (int i = 0; i < 8; ++i) {
                __bf16 hi = (__bf16)f[i];
                b_hi[i] = hi;
                b_lo[i] = (__bf16)(f[i] - (float)hi);
            }
            acc = __builtin_amdgcn_mfma_f32_16x16x32_bf16(a_hi[ks], b_hi, acc, 0, 0, 0);
            acc = __builtin_amdgcn_mfma_f32_16x16x32_bf16(a_lo[ks], b_hi, acc, 0, 0, 0);
            acc = __builtin_amdgcn_mfma_f32_16x16x32_bf16(a_hi[ks], b_lo, acc, 0, 0, 0);
        }

        int col = j0 + idx16;
        float bv = bias[col];
        #pragma unroll
        for (int r = 0; r < 4; ++r) {
            int row = m0 + kgrp * 4 + r;
            if (row < n)
                out[(size_t)row * D + col] = acc[r] + bv;
        }
    }
}

// ---------------- launch ----------------

extern "C" void kernel_launch(void* const* d_in, const int* in_sizes, int n_in,
                              void* d_out, int out_size, void* d_ws, size_t ws_size,
                              hipStream_t stream) {
    const float* feature = (const float*)d_in[0];
    const int*   src     = (const int*)d_in[1];
    const int*   dst     = (const int*)d_in[2];
    const float* W       = (const float*)d_in[3];
    const float* b       = (const float*)d_in[4];
    float*       out     = (float*)d_out;

    const int N = in_sizes[0] / D;
    const int E = in_sizes[1];

    // workspace layout
    char* w = (char*)d_ws;
    float* h        = (float*)w;                    w += (size_t)N * D * sizeof(float);
    int*   row_ptr  = (int*)w;                      w += (size_t)(N + 1) * sizeof(int);
    int*   cursor   = (int*)w;                      w += (size_t)N * sizeof(int);
    int*   deg      = (int*)w;                      w += (size_t)N * sizeof(int);
    int*   blocksum = (int*)w;                      w += (size_t)SCAN_NB * sizeof(int);
    int*   csr_src  = (int*)w;

    hipMemsetAsync(deg, 0, (size_t)N * sizeof(int), stream);

    int eblocks = (E + 255) / 256;
    hist_kernel<<<eblocks, 256, 0, stream>>>(dst, deg, E);
    scan_part_kernel<<<SCAN_NB, SCAN_BT, 0, stream>>>(deg, blocksum, N);
    scan_blocksum_kernel<<<1, SCAN_NB, 0, stream>>>(blocksum);
    scan_write_kernel<<<SCAN_NB, SCAN_BT, 0, stream>>>(deg, blocksum, row_ptr, cursor, N, E);
    fill_kernel<<<eblocks, 256, 0, stream>>>(src, dst, cursor, csr_src, E);

    agg_kernel<<<2048, 256, 0, stream>>>(feature, row_ptr, csr_src, h, N);

    int gblocks = (N + 63) / 64;
    gemm_mfma_kernel<<<gblocks, 256, 0, stream>>>(h, W, b, out, N);
}